// Round 1
// baseline (80.513 us; speedup 1.0000x reference)
//
#include <hip/hip_runtime.h>
#include <math.h>

#define NBINS 64
#define TPB 256

// ---------------------------------------------------------------------------
// Pass 1: per-row histogram of d = min(floor(|y_true|), 63)
// grid = (blocks_per_row, B); each block covers a contiguous chunk of one row.
// ---------------------------------------------------------------------------
__global__ __launch_bounds__(TPB) void hist_kernel(
    const float* __restrict__ y_true, unsigned int* __restrict__ counts, int T)
{
    __shared__ unsigned int lhist[NBINS];
    const int tid = threadIdx.x;
    if (tid < NBINS) lhist[tid] = 0u;
    __syncthreads();

    const int row = blockIdx.y;
    const int chunk = T / gridDim.x;                 // samples per block
    const long long base = (long long)row * T + (long long)blockIdx.x * chunk;
    const float4* __restrict__ p = (const float4*)(y_true + base);
    const int n4 = chunk >> 2;

    for (int i = tid; i < n4; i += TPB) {
        float4 v = p[i];
        atomicAdd(&lhist[min((int)fabsf(v.x), NBINS - 1)], 1u);
        atomicAdd(&lhist[min((int)fabsf(v.y), NBINS - 1)], 1u);
        atomicAdd(&lhist[min((int)fabsf(v.z), NBINS - 1)], 1u);
        atomicAdd(&lhist[min((int)fabsf(v.w), NBINS - 1)], 1u);
    }
    __syncthreads();

    if (tid < NBINS) {
        unsigned int c = lhist[tid];
        if (c) atomicAdd(&counts[row * NBINS + tid], c);
    }
}

// ---------------------------------------------------------------------------
// Pass 2: numerator = sum( (y_pred-y_true)^2 * invw[row][d] ), per-block
// double partials (deterministic tree reduce, no float atomics).
// ---------------------------------------------------------------------------
__global__ __launch_bounds__(TPB) void loss_kernel(
    const float* __restrict__ y_pred, const float* __restrict__ y_true,
    const unsigned int* __restrict__ counts, double* __restrict__ partial, int T)
{
    __shared__ float invw[NBINS];
    const int tid = threadIdx.x;
    const int row = blockIdx.y;
    if (tid < NBINS) {
        unsigned int c = counts[row * NBINS + tid];
        invw[tid] = c ? (1.0f / (float)c) : 0.0f;
    }
    __syncthreads();

    const int chunk = T / gridDim.x;
    const long long base = (long long)row * T + (long long)blockIdx.x * chunk;
    const float4* __restrict__ pp = (const float4*)(y_pred + base);
    const float4* __restrict__ pt = (const float4*)(y_true + base);
    const int n4 = chunk >> 2;

    double acc = 0.0;
    for (int i = tid; i < n4; i += TPB) {
        float4 vp = pp[i];
        float4 vt = pt[i];
        float e0 = vp.x - vt.x, e1 = vp.y - vt.y, e2 = vp.z - vt.z, e3 = vp.w - vt.w;
        acc += (double)(e0 * e0 * invw[min((int)fabsf(vt.x), NBINS - 1)]);
        acc += (double)(e1 * e1 * invw[min((int)fabsf(vt.y), NBINS - 1)]);
        acc += (double)(e2 * e2 * invw[min((int)fabsf(vt.z), NBINS - 1)]);
        acc += (double)(e3 * e3 * invw[min((int)fabsf(vt.w), NBINS - 1)]);
    }

    __shared__ double sdata[TPB];
    sdata[tid] = acc;
    __syncthreads();
    for (int s = TPB / 2; s > 0; s >>= 1) {
        if (tid < s) sdata[tid] += sdata[tid + s];
        __syncthreads();
    }
    if (tid == 0) partial[blockIdx.y * gridDim.x + blockIdx.x] = sdata[0];
}

// ---------------------------------------------------------------------------
// Final: reduce partials; den = # nonempty (row,bin) cells (== sum of weights
// exactly, since each nonempty cell contributes count * 1/count = 1).
// ---------------------------------------------------------------------------
__global__ __launch_bounds__(256) void final_kernel(
    const double* __restrict__ partial, int n_partial,
    const unsigned int* __restrict__ counts, int n_counts,
    float* __restrict__ out)
{
    const int tid = threadIdx.x;
    double num = 0.0, den = 0.0;
    for (int i = tid; i < n_partial; i += 256) num += partial[i];
    for (int i = tid; i < n_counts; i += 256) den += counts[i] ? 1.0 : 0.0;

    __shared__ double snum[256];
    __shared__ double sden[256];
    snum[tid] = num;
    sden[tid] = den;
    __syncthreads();
    for (int s = 128; s > 0; s >>= 1) {
        if (tid < s) { snum[tid] += snum[tid + s]; sden[tid] += sden[tid + s]; }
        __syncthreads();
    }
    if (tid == 0) {
        double wl = snum[0] / sden[0];
        out[0] = (float)sqrt(wl);
    }
}

extern "C" void kernel_launch(void* const* d_in, const int* in_sizes, int n_in,
                              void* d_out, int out_size, void* d_ws, size_t ws_size,
                              hipStream_t stream)
{
    const float* y_pred = (const float*)d_in[0];
    const float* y_true = (const float*)d_in[1];
    float* out = (float*)d_out;

    const int total = in_sizes[0];      // B * T
    const int B = 64;
    const int T = total / B;            // 524288

    // Workspace layout: [counts: B*NBINS u32][partials: B*bpr doubles]
    unsigned int* counts = (unsigned int*)d_ws;
    double* partial = (double*)((char*)d_ws + (size_t)B * NBINS * sizeof(unsigned int));

    const int bpr = 64;                 // blocks per row; T % (bpr*4) == 0
    dim3 grid(bpr, B);

    hipMemsetAsync(counts, 0, (size_t)B * NBINS * sizeof(unsigned int), stream);
    hist_kernel<<<grid, TPB, 0, stream>>>(y_true, counts, T);
    loss_kernel<<<grid, TPB, 0, stream>>>(y_pred, y_true, counts, partial, T);
    final_kernel<<<1, 256, 0, stream>>>(partial, bpr * B, counts, B * NBINS, out);
}